// Round 1
// baseline (185.900 us; speedup 1.0000x reference)
//
#include <hip/hip_runtime.h>
#include <hip/hip_bf16.h>

// Problem constants (fixed by the reference): N_CLASS=200, N_MU=1024, D=512, K=512
constexpr int N_CLASS = 200;
constexpr int N_MU    = 1024;
constexpr int DIM     = 512;
constexpr int KIN     = 512;
constexpr int NCAND   = N_MU + KIN;      // 1536 candidates
constexpr int SORTN   = 2048;            // next pow2

// ---------------------------------------------------------------------------
// Kernel 1: per-cls_idx-entry stable top-1024 selection via bitonic sort.
// Key = (~sortable(score) << 32) | index  -> ascending sort == descending
// score with lower-index-first tie break (matches XLA top_k stability).
// Writes selected candidate indices + bit-exact scores to workspace,
// and sets flags[c]=1.
// ---------------------------------------------------------------------------
__global__ __launch_bounds__(1024) void sort_kernel(
    const float* __restrict__ q_sc,    // [N_CLASS, N_MU]
    const float* __restrict__ inp_sc,  // [KIN, N_CLASS]
    const int*   __restrict__ cls_idx, // [n_idx]
    int*         __restrict__ ws_idx,  // [n_idx, N_MU]
    float*       __restrict__ ws_sc,   // [n_idx, N_MU]
    int*         __restrict__ flags)   // [N_CLASS]
{
    __shared__ unsigned long long keys[SORTN];
    const int e = blockIdx.x;
    const int c = cls_idx[e];
    const int t = threadIdx.x;

    for (int i = t; i < SORTN; i += 1024) {
        unsigned long long key;
        if (i < NCAND) {
            float f = (i < N_MU) ? q_sc[(size_t)c * N_MU + i]
                                 : inp_sc[(size_t)(i - N_MU) * N_CLASS + c];
            unsigned u = __float_as_uint(f);
            // monotone map float -> ascending uint
            unsigned s = (u & 0x80000000u) ? ~u : (u | 0x80000000u);
            unsigned inv = ~s; // descending
            key = ((unsigned long long)inv << 32) | (unsigned)i;
        } else {
            key = 0xFFFFFFFFFFFFFFFFull; // pad sorts last
        }
        keys[i] = key;
    }
    __syncthreads();

    // bitonic sort, ascending, 2048 elements, 1024 threads (1 pair each/step)
    for (int k = 2; k <= SORTN; k <<= 1) {
        for (int j = k >> 1; j > 0; j >>= 1) {
            const int i = ((t & ~(j - 1)) << 1) | (t & (j - 1));
            const int p = i | j;
            const bool asc = ((i & k) == 0);
            unsigned long long a = keys[i], b = keys[p];
            const bool sw = asc ? (a > b) : (a < b);
            if (sw) { keys[i] = b; keys[p] = a; }
            __syncthreads();
        }
    }

    // slots 0..1023 hold the top-1024 (descending score, stable)
    {
        unsigned long long key = keys[t];
        int idx = (int)(key & 0xFFFFFFFFu);
        unsigned s = ~((unsigned)(key >> 32));
        unsigned u = (s & 0x80000000u) ? (s & 0x7FFFFFFFu) : ~s;
        ws_idx[((size_t)e << 10) + t] = idx;
        ws_sc [((size_t)e << 10) + t] = __uint_as_float(u);
    }
    if (t == 0) flags[c] = 1;
}

// ---------------------------------------------------------------------------
// Kernel 2: fill output for classes NOT listed in cls_idx (flag==0).
// With cls_idx = arange(N_CLASS) every block exits immediately.
// ---------------------------------------------------------------------------
__global__ __launch_bounds__(256) void fill_kernel(
    const float* __restrict__ q_mu,   // [N_CLASS, N_MU, DIM]
    const float* __restrict__ q_sc,   // [N_CLASS, N_MU]
    const int*   __restrict__ flags,
    float*       __restrict__ out)    // [N_CLASS, N_MU, DIM+1]
{
    const int b = blockIdx.x;
    const int c = b >> 8;
    if (flags[c] != 0) return;
    const int j0 = (b & 255) << 2; // 4 rows per block
    const int t = threadIdx.x;
    const size_t base = ((size_t)c << 10) + j0;
    for (int l = t; l < 4 * (DIM + 1); l += 256) {
        const int r = l / (DIM + 1);
        const int q = l - r * (DIM + 1);
        const size_t row = base + r;
        float v = (q < DIM) ? q_mu[row * DIM + q] : q_sc[row];
        out[base * (DIM + 1) + l] = v;
    }
}

// ---------------------------------------------------------------------------
// Kernel 3: gather mu rows + scores into output. 4 rows (2052 floats,
// 16B-aligned region) staged in LDS so global stores are float4 despite the
// 513-float row stride.
// ---------------------------------------------------------------------------
__global__ __launch_bounds__(256) void gather_kernel(
    const float* __restrict__ q_mu,   // [N_CLASS, N_MU, DIM]
    const float* __restrict__ inp_mu, // [KIN, DIM]
    const int*   __restrict__ cls_idx,
    const int*   __restrict__ ws_idx, // [n_idx, N_MU]
    const float* __restrict__ ws_sc,  // [n_idx, N_MU]
    float*       __restrict__ out)    // [N_CLASS, N_MU, DIM+1]
{
    __shared__ float buf[4 * (DIM + 1)]; // 2052 floats, laid out as output
    const int b  = blockIdx.x;
    const int e  = b >> 8;          // cls_idx entry
    const int g  = b & 255;         // 4-row group within the class
    const int c  = cls_idx[e];
    const int j0 = g << 2;
    const int t  = threadIdx.x;

    // load 4 gathered rows as float4 into LDS (output layout)
    for (int l = t; l < 4 * (DIM / 4); l += 256) { // 512 float4 loads
        const int r = l >> 7;         // row 0..3
        const int q = l & 127;        // float4 index within row
        const int idx = ws_idx[((size_t)e << 10) + j0 + r];
        const float4* src = (idx < N_MU)
            ? (const float4*)(q_mu + (((size_t)c << 10) + idx) * DIM)
            : (const float4*)(inp_mu + (size_t)(idx - N_MU) * DIM);
        float4 v = src[q];
        float* d = buf + r * (DIM + 1) + q * 4;
        d[0] = v.x; d[1] = v.y; d[2] = v.z; d[3] = v.w;
    }
    if (t < 4) buf[t * (DIM + 1) + DIM] = ws_sc[((size_t)e << 10) + j0 + t];
    __syncthreads();

    // stream the 2052-float region out as 513 float4 stores (16B aligned:
    // group byte offset = ((c<<10)+j0)*513*4, j0 % 4 == 0 -> multiple of 16)
    float4* dst = (float4*)(out + (((size_t)c << 10) + j0) * (DIM + 1));
    for (int l = t; l < (DIM + 1); l += 256) {
        dst[l] = *(const float4*)(buf + l * 4);
    }
}

extern "C" void kernel_launch(void* const* d_in, const int* in_sizes, int n_in,
                              void* d_out, int out_size, void* d_ws, size_t ws_size,
                              hipStream_t stream) {
    const float* q_mu    = (const float*)d_in[0];
    const float* q_sc    = (const float*)d_in[1];
    const float* inp_mu  = (const float*)d_in[2];
    const float* inp_sc  = (const float*)d_in[3];
    const int*   cls_idx = (const int*)d_in[4];
    float* out = (float*)d_out;
    const int n_idx = in_sizes[4];

    // workspace layout: [n_idx*N_MU int] ws_idx | [n_idx*N_MU float] ws_sc | [N_CLASS int] flags
    int*   ws_idx = (int*)d_ws;
    float* ws_sc  = (float*)((char*)d_ws + (size_t)n_idx * N_MU * sizeof(int));
    int*   flags  = (int*)((char*)d_ws + (size_t)n_idx * N_MU * (sizeof(int) + sizeof(float)));

    hipMemsetAsync(flags, 0, N_CLASS * sizeof(int), stream);
    sort_kernel<<<n_idx, 1024, 0, stream>>>(q_sc, inp_sc, cls_idx, ws_idx, ws_sc, flags);
    fill_kernel<<<N_CLASS * 256, 256, 0, stream>>>(q_mu, q_sc, flags, out);
    gather_kernel<<<n_idx * 256, 256, 0, stream>>>(q_mu, inp_mu, cls_idx, ws_idx, ws_sc, out);
}

// Round 3
// 155.516 us; speedup vs baseline: 1.1954x; 1.1954x over previous
//
#include <hip/hip_runtime.h>
#include <hip/hip_bf16.h>

// Problem constants (fixed by the reference): N_CLASS=200, N_MU=1024, D=512, K=512
constexpr int N_CLASS = 200;
constexpr int N_MU    = 1024;
constexpr int DIM     = 512;
constexpr int KIN     = 512;
constexpr int NCAND   = N_MU + KIN;      // 1536 candidates
constexpr int SORTN   = 2048;            // next pow2
constexpr int RPB     = 8;               // rows per output block

// clang ext-vector (NOT HIP_vector_type) so __builtin_nontemporal_* accepts it
typedef float f4 __attribute__((ext_vector_type(4)));

// ---------------------------------------------------------------------------
// Kernel 1: per-class stable top-1024 selection via bitonic sort.
// Key = (~sortable(score) << 32) | index  -> ascending sort == descending
// score with lower-index-first tie break (matches XLA top_k stability).
// Workspace indexed by CLASS id c so the output kernel needs no
// entry->class mapping. Sets flags[c]=1.
// ---------------------------------------------------------------------------
__global__ __launch_bounds__(1024) void sort_kernel(
    const float* __restrict__ q_sc,    // [N_CLASS, N_MU]
    const float* __restrict__ inp_sc,  // [KIN, N_CLASS]
    const int*   __restrict__ cls_idx, // [n_idx]
    int*         __restrict__ ws_idx,  // [N_CLASS, N_MU]
    float*       __restrict__ ws_sc,   // [N_CLASS, N_MU]
    int*         __restrict__ flags)   // [N_CLASS]
{
    __shared__ unsigned long long keys[SORTN];
    const int e = blockIdx.x;
    const int c = cls_idx[e];
    const int t = threadIdx.x;

    for (int i = t; i < SORTN; i += 1024) {
        unsigned long long key;
        if (i < NCAND) {
            float f = (i < N_MU) ? q_sc[(size_t)c * N_MU + i]
                                 : inp_sc[(size_t)(i - N_MU) * N_CLASS + c];
            unsigned u = __float_as_uint(f);
            unsigned s = (u & 0x80000000u) ? ~u : (u | 0x80000000u);
            unsigned inv = ~s; // descending
            key = ((unsigned long long)inv << 32) | (unsigned)i;
        } else {
            key = 0xFFFFFFFFFFFFFFFFull; // pad sorts last
        }
        keys[i] = key;
    }
    __syncthreads();

    for (int k = 2; k <= SORTN; k <<= 1) {
        for (int j = k >> 1; j > 0; j >>= 1) {
            const int i = ((t & ~(j - 1)) << 1) | (t & (j - 1));
            const int p = i | j;
            const bool asc = ((i & k) == 0);
            unsigned long long a = keys[i], b = keys[p];
            const bool sw = asc ? (a > b) : (a < b);
            if (sw) { keys[i] = b; keys[p] = a; }
            __syncthreads();
        }
    }

    {
        unsigned long long key = keys[t];
        int idx = (int)(key & 0xFFFFFFFFu);
        unsigned s = ~((unsigned)(key >> 32));
        unsigned u = (s & 0x80000000u) ? (s & 0x7FFFFFFFu) : ~s;
        ws_idx[((size_t)c << 10) + t] = idx;
        ws_sc [((size_t)c << 10) + t] = __uint_as_float(u);
    }
    if (t == 0) flags[c] = 1;
}

// ---------------------------------------------------------------------------
// Kernel 2 (fused gather+fill): one block per (class, 8-row group).
// flag[c]==1 -> gather selected rows via ws_idx; flag[c]==0 -> passthrough
// copy of the original queue. 8 rows (4104 floats = 16416 B = 1026 f4,
// 16B-aligned region) staged in LDS so global stores vectorize despite the
// 513-float row stride. Touch-once streams are nontemporal to keep L2 for
// inp_mu (1 MB, reused ~200x).
// ---------------------------------------------------------------------------
__global__ __launch_bounds__(256) void out_kernel(
    const float* __restrict__ q_mu,   // [N_CLASS, N_MU, DIM]
    const float* __restrict__ q_sc,   // [N_CLASS, N_MU]
    const float* __restrict__ inp_mu, // [KIN, DIM]
    const int*   __restrict__ ws_idx, // [N_CLASS, N_MU]
    const float* __restrict__ ws_sc,  // [N_CLASS, N_MU]
    const int*   __restrict__ flags,  // [N_CLASS]
    float*       __restrict__ out)    // [N_CLASS, N_MU, DIM+1]
{
    __shared__ __align__(16) float buf[RPB * (DIM + 1)]; // 4104 floats
    const int b  = blockIdx.x;
    const int c  = b >> 7;          // 128 groups per class
    const int g  = b & 127;
    const int j0 = g * RPB;
    const int t  = threadIdx.x;
    const bool upd = (flags[c] != 0);
    const size_t rowbase = ((size_t)c << 10) + j0;

#pragma unroll
    for (int it = 0; it < 4; ++it) {
        const int l = t + it * 256;     // 0..1023
        const int r = l >> 7;           // row 0..7
        const int q = l & 127;          // f4 index within row
        f4 v;
        if (upd) {
            const int idx = ws_idx[rowbase + r];
            if (idx < N_MU) {
                v = __builtin_nontemporal_load(
                    (const f4*)(q_mu + (((size_t)c << 10) + idx) * DIM) + q);
            } else {
                v = ((const f4*)(inp_mu + (size_t)(idx - N_MU) * DIM))[q];
            }
        } else {
            v = __builtin_nontemporal_load(
                (const f4*)(q_mu + (rowbase + r) * DIM) + q);
        }
        float* d = buf + r * (DIM + 1) + q * 4; // only 4B-aligned for odd r
        d[0] = v.x; d[1] = v.y; d[2] = v.z; d[3] = v.w;
    }
    if (t < RPB) {
        buf[t * (DIM + 1) + DIM] = upd ? ws_sc[rowbase + t] : q_sc[rowbase + t];
    }
    __syncthreads();

    f4* dst = (f4*)(out + rowbase * (DIM + 1));
    for (int l = t; l < RPB * (DIM + 1) / 4; l += 256) {
        __builtin_nontemporal_store(*(const f4*)(buf + l * 4), dst + l);
    }
}

extern "C" void kernel_launch(void* const* d_in, const int* in_sizes, int n_in,
                              void* d_out, int out_size, void* d_ws, size_t ws_size,
                              hipStream_t stream) {
    const float* q_mu    = (const float*)d_in[0];
    const float* q_sc    = (const float*)d_in[1];
    const float* inp_mu  = (const float*)d_in[2];
    const float* inp_sc  = (const float*)d_in[3];
    const int*   cls_idx = (const int*)d_in[4];
    float* out = (float*)d_out;
    const int n_idx = in_sizes[4];

    // workspace: [N_CLASS*N_MU int] ws_idx | [N_CLASS*N_MU float] ws_sc | [N_CLASS int] flags
    int*   ws_idx = (int*)d_ws;
    float* ws_sc  = (float*)((char*)d_ws + (size_t)N_CLASS * N_MU * sizeof(int));
    int*   flags  = (int*)((char*)d_ws + (size_t)N_CLASS * N_MU * (sizeof(int) + sizeof(float)));

    (void)hipMemsetAsync(flags, 0, N_CLASS * sizeof(int), stream);
    sort_kernel<<<n_idx, 1024, 0, stream>>>(q_sc, inp_sc, cls_idx, ws_idx, ws_sc, flags);
    out_kernel<<<N_CLASS * (N_MU / RPB), 256, 0, stream>>>(
        q_mu, q_sc, inp_mu, ws_idx, ws_sc, flags, out);
}